// Round 1
// baseline (698.547 us; speedup 1.0000x reference)
//
#include <hip/hip_runtime.h>
#include <hip/hip_bf16.h>
#include <stdint.h>

// Problem constants
#define T_TOK 8192
#define DIM 4096
#define ODIM 4096
#define NL 8
#define RANK 16
#define KAUG 4224   // DIM + NL*RANK

// ---------- helpers ----------
__device__ __forceinline__ uint16_t f2b(float x) {
    uint32_t u = __builtin_bit_cast(uint32_t, x);
    u += 0x7fffu + ((u >> 16) & 1u);   // RNE
    return (uint16_t)(u >> 16);
}
__device__ __forceinline__ float b2f(uint16_t u) {
    uint32_t v = ((uint32_t)u) << 16;
    return __builtin_bit_cast(float, v);
}

typedef __attribute__((ext_vector_type(4))) float floatx4;
typedef __attribute__((ext_vector_type(8))) __bf16 bf16x8;

__device__ __forceinline__ void load_lds16(const uint16_t* g, uint16_t* l) {
    __builtin_amdgcn_global_load_lds(
        (const __attribute__((address_space(1))) uint32_t*)g,
        (__attribute__((address_space(3))) uint32_t*)l, 16, 0, 0);
}

// ---------- kernel 1: pack W + lora_b into w_aug (bf16, [ODIM][KAUG]) ----------
__global__ __launch_bounds__(256) void pack_w(const float* __restrict__ W,
                                              const float* __restrict__ lora_b,
                                              uint16_t* __restrict__ waug) {
    int o = blockIdx.x;          // 0..4095
    int tid = threadIdx.x;       // 0..255
    const float4* src = (const float4*)(W + (size_t)o * DIM);
    uint16_t* dst = waug + (size_t)o * KAUG;
#pragma unroll
    for (int k = 0; k < 4; ++k) {
        int i4 = k * 256 + tid;              // float4 index within row (1024 total)
        float4 v = src[i4];
        ushort4 bv;
        bv.x = f2b(v.x); bv.y = f2b(v.y); bv.z = f2b(v.z); bv.w = f2b(v.w);
        *(ushort4*)(dst + (size_t)i4 * 4) = bv;
    }
    if (tid < NL * RANK) {
        int l = tid >> 4, r = tid & 15;
        float v = lora_b[((size_t)l * ODIM + o) * RANK + r];
        dst[DIM + tid] = f2b(v);
    }
}

// ---------- kernel 2: pack x base cols into x_aug; lora_a into a_all ----------
__global__ __launch_bounds__(256) void pack_x(const float* __restrict__ x,
                                              const float* __restrict__ lora_a,
                                              uint16_t* __restrict__ xaug,
                                              uint16_t* __restrict__ aall) {
    int b = blockIdx.x;          // 0..8191 x-rows, 8192..8319 a-rows
    int tid = threadIdx.x;
    const float* src;
    uint16_t* dst;
    if (b < T_TOK) { src = x + (size_t)b * DIM;            dst = xaug + (size_t)b * KAUG; }
    else           { int rr = b - T_TOK;
                     src = lora_a + (size_t)rr * DIM;       dst = aall + (size_t)rr * DIM; }
#pragma unroll
    for (int k = 0; k < 4; ++k) {
        int i4 = k * 256 + tid;
        float4 v = ((const float4*)src)[i4];
        ushort4 bv;
        bv.x = f2b(v.x); bv.y = f2b(v.y); bv.z = f2b(v.z); bv.w = f2b(v.w);
        *(ushort4*)(dst + (size_t)i4 * 4) = bv;
    }
}

// ---------- kernel 3: per-token shrink s = x . A[l]^T, fill masked aug cols ----------
__global__ __launch_bounds__(256) void shrink_fill(uint16_t* __restrict__ xaug,
                                                   const uint16_t* __restrict__ aall,
                                                   const int* __restrict__ idx) {
    int tid = threadIdx.x;
    int lane = tid & 63, wid = tid >> 6;
    int t = blockIdx.x * 4 + wid;           // one wave per token
    int l = idx[t];
    const uint16_t* xr = xaug + (size_t)t * KAUG;
    float acc[RANK];
#pragma unroll
    for (int r = 0; r < RANK; ++r) acc[r] = 0.f;

    for (int it = 0; it < 16; ++it) {
        int e = (it * 64 + lane) * 4;       // element index (4 bf16 at a time)
        ushort4 xv = *(const ushort4*)(xr + e);
        float x0 = b2f(xv.x), x1 = b2f(xv.y), x2 = b2f(xv.z), x3 = b2f(xv.w);
#pragma unroll
        for (int r = 0; r < RANK; ++r) {
            ushort4 av = *(const ushort4*)(aall + (size_t)(l * RANK + r) * DIM + e);
            acc[r] += x0 * b2f(av.x) + x1 * b2f(av.y) + x2 * b2f(av.z) + x3 * b2f(av.w);
        }
    }
    // butterfly-reduce each accumulator across the wave -> all lanes hold full sums
#pragma unroll
    for (int r = 0; r < RANK; ++r) {
        float v = acc[r];
#pragma unroll
        for (int off = 32; off > 0; off >>= 1) v += __shfl_xor(v, off, 64);
        acc[r] = v;
    }
    // each lane writes 2 of the 128 aug cols (masked one-hot by adapter)
    uint16_t* dst = xaug + (size_t)t * KAUG + DIM;
#pragma unroll
    for (int k = 0; k < 2; ++k) {
        int p = lane * 2 + k;
        int pl = p >> 4, pr = p & 15;
        float v = 0.f;
#pragma unroll
        for (int r = 0; r < RANK; ++r)
            if (pr == r) v = acc[r];
        dst[p] = (pl == l) ? f2b(v) : (uint16_t)0;
    }
}

// ---------- kernel 4: bf16 NT GEMM, C[t,o] = sum_k A[t,k]*B[o,k] ----------
#define BM 128
#define BN 128
#define BK 32

__global__ __launch_bounds__(256) void gemm_aug(const uint16_t* __restrict__ A,
                                                const uint16_t* __restrict__ B,
                                                float* __restrict__ C,
                                                int M, int N, int K) {
    __shared__ uint16_t sA[BM * BK];   // [row 128][k 32], row-major, unpadded
    __shared__ uint16_t sB[BN * BK];

    int tid = threadIdx.x;
    int lane = tid & 63, wid = tid >> 6;
    int bn = blockIdx.x, bm = blockIdx.y;
    int wm = (wid & 1) * 64, wn = (wid >> 1) * 64;
    int q = lane >> 4, r16 = lane & 15;

    // staging: chunk c = 16B; call0 chunks = tid, call1 chunks = 256+tid
    int rowS = tid >> 2;                 // 0..63
    int kpos = (tid & 3) * 8;            // element offset inside row
    const uint16_t* gA0 = A + (size_t)(bm * BM + rowS) * K + kpos;
    const uint16_t* gA1 = A + (size_t)(bm * BM + 64 + rowS) * K + kpos;
    const uint16_t* gB0 = B + (size_t)(bn * BN + rowS) * K + kpos;
    const uint16_t* gB1 = B + (size_t)(bn * BN + 64 + rowS) * K + kpos;
    uint16_t* lA0 = sA + wid * 512;          // wave-uniform LDS bases
    uint16_t* lA1 = sA + 2048 + wid * 512;
    uint16_t* lB0 = sB + wid * 512;
    uint16_t* lB1 = sB + 2048 + wid * 512;

    floatx4 acc[4][4];
#pragma unroll
    for (int i = 0; i < 4; ++i)
#pragma unroll
        for (int j = 0; j < 4; ++j) acc[i][j] = (floatx4){0.f, 0.f, 0.f, 0.f};

    for (int k0 = 0; k0 < K; k0 += BK) {
        __syncthreads();                  // protect LDS from prior-iter readers
        load_lds16(gA0 + k0, lA0);
        load_lds16(gA1 + k0, lA1);
        load_lds16(gB0 + k0, lB0);
        load_lds16(gB1 + k0, lB1);
        __syncthreads();                  // drains vmcnt before barrier

        bf16x8 af[4], bfr[4];
#pragma unroll
        for (int i = 0; i < 4; ++i)
            af[i] = *(const bf16x8*)(sA + (size_t)(wm + i * 16 + r16) * BK + q * 8);
#pragma unroll
        for (int j = 0; j < 4; ++j)
            bfr[j] = *(const bf16x8*)(sB + (size_t)(wn + j * 16 + r16) * BK + q * 8);
#pragma unroll
        for (int i = 0; i < 4; ++i)
#pragma unroll
            for (int j = 0; j < 4; ++j)
                acc[i][j] = __builtin_amdgcn_mfma_f32_16x16x32_bf16(af[i], bfr[j], acc[i][j], 0, 0, 0);
    }

    // epilogue: C/D mapping col = lane&15, row = (lane>>4)*4 + reg  [m89-verified]
#pragma unroll
    for (int i = 0; i < 4; ++i) {
#pragma unroll
        for (int j = 0; j < 4; ++j) {
            int col = bn * BN + wn + j * 16 + r16;
#pragma unroll
            for (int e = 0; e < 4; ++e) {
                int row = bm * BM + wm + i * 16 + q * 4 + e;
                C[(size_t)row * N + col] = acc[i][j][e];
            }
        }
    }
}

// ---------- launcher ----------
extern "C" void kernel_launch(void* const* d_in, const int* in_sizes, int n_in,
                              void* d_out, int out_size, void* d_ws, size_t ws_size,
                              hipStream_t stream) {
    const float* x  = (const float*)d_in[0];
    const float* W  = (const float*)d_in[1];
    const float* la = (const float*)d_in[2];
    const float* lb = (const float*)d_in[3];
    const int* idx  = (const int*)d_in[4];
    float* out = (float*)d_out;

    uint16_t* xaug = (uint16_t*)d_ws;                         // [8192][4224] bf16
    uint16_t* waug = xaug + (size_t)T_TOK * KAUG;             // [4096][4224] bf16
    uint16_t* aall = waug + (size_t)ODIM * KAUG;              // [128][4096]  bf16
    // total ws use: (8192+4096)*4224*2 + 128*4096*2 = ~100 MiB

    hipLaunchKernelGGL(pack_w, dim3(ODIM), dim3(256), 0, stream, W, lb, waug);
    hipLaunchKernelGGL(pack_x, dim3(T_TOK + NL * RANK), dim3(256), 0, stream, x, la, xaug, aall);
    hipLaunchKernelGGL(shrink_fill, dim3(T_TOK / 4), dim3(256), 0, stream, xaug, aall, idx);
    hipLaunchKernelGGL(gemm_aug, dim3(ODIM / BN, T_TOK / BM), dim3(256), 0, stream,
                       xaug, waug, out, T_TOK, ODIM, KAUG);
}

// Round 2
// 611.729 us; speedup vs baseline: 1.1419x; 1.1419x over previous
//
#include <hip/hip_runtime.h>
#include <hip/hip_bf16.h>
#include <stdint.h>

// Problem constants
#define T_TOK 8192
#define DIM 4096
#define ODIM 4096
#define NL 8
#define RANK 16
#define KAUG 4224   // DIM + NL*RANK

// ---------- helpers ----------
__device__ __forceinline__ uint16_t f2b(float x) {
    uint32_t u = __builtin_bit_cast(uint32_t, x);
    u += 0x7fffu + ((u >> 16) & 1u);   // RNE
    return (uint16_t)(u >> 16);
}

typedef __attribute__((ext_vector_type(4))) float floatx4;
typedef __attribute__((ext_vector_type(8))) __bf16 bf16x8;

__device__ __forceinline__ void load_lds16(const uint16_t* g, uint16_t* l) {
    __builtin_amdgcn_global_load_lds(
        (const __attribute__((address_space(1))) uint32_t*)g,
        (__attribute__((address_space(3))) uint32_t*)l, 16, 0, 0);
}

// ---------- kernel 1: fused pack of all bf16 operands ----------
// blocks [0,4096): W row -> waug base cols + lora_b -> waug aug cols
// blocks [4096,12288): x row -> xaug base cols
// blocks [12288,12416): lora_a row -> aall
__global__ __launch_bounds__(256) void pack_all(const float* __restrict__ x,
                                                const float* __restrict__ W,
                                                const float* __restrict__ la,
                                                const float* __restrict__ lb,
                                                uint16_t* __restrict__ xaug,
                                                uint16_t* __restrict__ waug,
                                                uint16_t* __restrict__ aall) {
    int b = blockIdx.x;
    int tid = threadIdx.x;
    const float* src;
    uint16_t* dst;
    if (b < ODIM)               { src = W  + (size_t)b * DIM;                 dst = waug + (size_t)b * KAUG; }
    else if (b < ODIM + T_TOK)  { int t = b - ODIM;
                                  src = x  + (size_t)t * DIM;                 dst = xaug + (size_t)t * KAUG; }
    else                        { int r = b - ODIM - T_TOK;
                                  src = la + (size_t)r * DIM;                 dst = aall + (size_t)r * DIM; }
#pragma unroll
    for (int k = 0; k < 4; ++k) {
        int i4 = k * 256 + tid;
        float4 v = ((const float4*)src)[i4];
        ushort4 bv;
        bv.x = f2b(v.x); bv.y = f2b(v.y); bv.z = f2b(v.z); bv.w = f2b(v.w);
        *(ushort4*)(dst + (size_t)i4 * 4) = bv;
    }
    if (b < ODIM && tid < NL * RANK) {
        int l = tid >> 4, r = tid & 15;
        dst[DIM + tid] = f2b(lb[((size_t)l * ODIM + b) * RANK + r]);
    }
}

// ---------- kernel 2: MFMA shrink  S_all = x . A_all^T, masked write of aug cols ----------
// BM=32 tokens per block, N=128 (all 8 adapters x rank 16), K=4096, BK=64
#define SBM 32
__global__ __launch_bounds__(256) void shrink_gemm(const uint16_t* __restrict__ xa,
                                                   const uint16_t* __restrict__ aall,
                                                   const int* __restrict__ idx,
                                                   uint16_t* __restrict__ xaug) {
    __shared__ uint16_t sA[SBM * 64];   // 4 KB
    __shared__ uint16_t sB[128 * 64];   // 16 KB
    int tid = threadIdx.x, lane = tid & 63, wid = tid >> 6;
    int bm = blockIdx.x;
    int q = lane >> 4, r16 = lane & 15;

    // staging: swizzled k-chunk so LDS rows are bank-rotated
    int rS = tid >> 3;                       // 0..31
    int kcS = (tid & 7) ^ (rS & 7);          // permuted 16B chunk within row
    const uint16_t* gA = xa + (size_t)(bm * SBM + rS) * KAUG + kcS * 8;
    const uint16_t* gB0 = aall + (size_t)(rS) * DIM + kcS * 8;
    const uint16_t* gB1 = aall + (size_t)(32 + rS) * DIM + kcS * 8;
    const uint16_t* gB2 = aall + (size_t)(64 + rS) * DIM + kcS * 8;
    const uint16_t* gB3 = aall + (size_t)(96 + rS) * DIM + kcS * 8;
    uint16_t* lA  = sA + wid * 512;
    uint16_t* lB0 = sB + wid * 512;
    uint16_t* lB1 = sB + 2048 + wid * 512;
    uint16_t* lB2 = sB + 4096 + wid * 512;
    uint16_t* lB3 = sB + 6144 + wid * 512;

    int sw0 = (q ^ (r16 & 7)) * 8;           // element offset of chunk q, kk=0
    int sw1 = ((4 + q) ^ (r16 & 7)) * 8;     // kk=1

    floatx4 acc[2][2];
#pragma unroll
    for (int i = 0; i < 2; ++i)
#pragma unroll
        for (int j = 0; j < 2; ++j) acc[i][j] = (floatx4){0.f, 0.f, 0.f, 0.f};

    for (int k0 = 0; k0 < DIM; k0 += 64) {
        __syncthreads();
        load_lds16(gA + k0, lA);
        load_lds16(gB0 + k0, lB0);
        load_lds16(gB1 + k0, lB1);
        load_lds16(gB2 + k0, lB2);
        load_lds16(gB3 + k0, lB3);
        __syncthreads();
#pragma unroll
        for (int kk = 0; kk < 2; ++kk) {
            int sw = kk ? sw1 : sw0;
            bf16x8 af[2], bv[2];
#pragma unroll
            for (int i = 0; i < 2; ++i)
                af[i] = *(const bf16x8*)(sA + (i * 16 + r16) * 64 + sw);
#pragma unroll
            for (int j = 0; j < 2; ++j)
                bv[j] = *(const bf16x8*)(sB + (wid * 32 + j * 16 + r16) * 64 + sw);
#pragma unroll
            for (int i = 0; i < 2; ++i)
#pragma unroll
                for (int j = 0; j < 2; ++j)
                    acc[i][j] = __builtin_amdgcn_mfma_f32_16x16x32_bf16(af[i], bv[j], acc[i][j], 0, 0, 0);
        }
    }
    // epilogue: masked one-hot select, write bf16 aug cols
#pragma unroll
    for (int i = 0; i < 2; ++i) {
#pragma unroll
        for (int j = 0; j < 2; ++j) {
            int p = wid * 32 + j * 16 + r16;   // 0..127
            int lp = p >> 4;
#pragma unroll
            for (int e = 0; e < 4; ++e) {
                int t = bm * SBM + i * 16 + q * 4 + e;
                uint16_t v = (idx[t] == lp) ? f2b(acc[i][j][e]) : (uint16_t)0;
                xaug[(size_t)t * KAUG + DIM + p] = v;
            }
        }
    }
}

// ---------- kernel 3: bf16 NT GEMM, C[t,o] = sum_k A[t,k]*B[o,k], BK=64 swizzled ----------
#define BM 128
#define BN 128

__global__ __launch_bounds__(256) void gemm_aug(const uint16_t* __restrict__ A,
                                                const uint16_t* __restrict__ B,
                                                float* __restrict__ C) {
    __shared__ uint16_t sA[BM * 64];   // 16 KB
    __shared__ uint16_t sB[BN * 64];   // 16 KB

    int tid = threadIdx.x, lane = tid & 63, wid = tid >> 6;
    int bn = blockIdx.x, bm = blockIdx.y;
    int wm = (wid & 1) * 64, wn = (wid >> 1) * 64;
    int q = lane >> 4, r16 = lane & 15;

    int rS = tid >> 3;                       // 0..31
    int kcS = (tid & 7) ^ (rS & 7);          // swizzled 16B chunk
    const uint16_t* gA[4];
    const uint16_t* gB[4];
    uint16_t* lA[4];
    uint16_t* lB[4];
#pragma unroll
    for (int c = 0; c < 4; ++c) {
        gA[c] = A + (size_t)(bm * BM + c * 32 + rS) * KAUG + kcS * 8;
        gB[c] = B + (size_t)(bn * BN + c * 32 + rS) * KAUG + kcS * 8;
        lA[c] = sA + c * 2048 + wid * 512;
        lB[c] = sB + c * 2048 + wid * 512;
    }

    int sw0 = (q ^ (r16 & 7)) * 8;
    int sw1 = ((4 + q) ^ (r16 & 7)) * 8;

    floatx4 acc[4][4];
#pragma unroll
    for (int i = 0; i < 4; ++i)
#pragma unroll
        for (int j = 0; j < 4; ++j) acc[i][j] = (floatx4){0.f, 0.f, 0.f, 0.f};

    for (int k0 = 0; k0 < KAUG; k0 += 64) {
        __syncthreads();
#pragma unroll
        for (int c = 0; c < 4; ++c) {
            load_lds16(gA[c] + k0, lA[c]);
            load_lds16(gB[c] + k0, lB[c]);
        }
        __syncthreads();
#pragma unroll
        for (int kk = 0; kk < 2; ++kk) {
            int sw = kk ? sw1 : sw0;
            bf16x8 af[4], bv[4];
#pragma unroll
            for (int i = 0; i < 4; ++i)
                af[i] = *(const bf16x8*)(sA + (wm + i * 16 + r16) * 64 + sw);
#pragma unroll
            for (int j = 0; j < 4; ++j)
                bv[j] = *(const bf16x8*)(sB + (wn + j * 16 + r16) * 64 + sw);
#pragma unroll
            for (int i = 0; i < 4; ++i)
#pragma unroll
                for (int j = 0; j < 4; ++j)
                    acc[i][j] = __builtin_amdgcn_mfma_f32_16x16x32_bf16(af[i], bv[j], acc[i][j], 0, 0, 0);
        }
    }

    // epilogue: C/D mapping col = lane&15, row = (lane>>4)*4 + reg  [m89-verified]
#pragma unroll
    for (int i = 0; i < 4; ++i) {
#pragma unroll
        for (int j = 0; j < 4; ++j) {
            int col = bn * BN + wn + j * 16 + r16;
#pragma unroll
            for (int e = 0; e < 4; ++e) {
                int row = bm * BM + wm + i * 16 + q * 4 + e;
                C[(size_t)row * ODIM + col] = acc[i][j][e];
            }
        }
    }
}

// ---------- launcher ----------
extern "C" void kernel_launch(void* const* d_in, const int* in_sizes, int n_in,
                              void* d_out, int out_size, void* d_ws, size_t ws_size,
                              hipStream_t stream) {
    const float* x  = (const float*)d_in[0];
    const float* W  = (const float*)d_in[1];
    const float* la = (const float*)d_in[2];
    const float* lb = (const float*)d_in[3];
    const int* idx  = (const int*)d_in[4];
    float* out = (float*)d_out;

    uint16_t* xaug = (uint16_t*)d_ws;                         // [8192][4224] bf16
    uint16_t* waug = xaug + (size_t)T_TOK * KAUG;             // [4096][4224] bf16
    uint16_t* aall = waug + (size_t)ODIM * KAUG;              // [128][4096]  bf16
    // total ws use: (8192+4096)*4224*2 + 128*4096*2 = ~100 MiB

    hipLaunchKernelGGL(pack_all, dim3(ODIM + T_TOK + NL * RANK), dim3(256), 0, stream,
                       x, W, la, lb, xaug, waug, aall);
    hipLaunchKernelGGL(shrink_gemm, dim3(T_TOK / SBM), dim3(256), 0, stream,
                       xaug, aall, idx, xaug);
    hipLaunchKernelGGL(gemm_aug, dim3(ODIM / BN, T_TOK / BM), dim3(256), 0, stream,
                       xaug, waug, out);
}